// Round 3
// baseline (65.903 us; speedup 1.0000x reference)
//
#include <hip/hip_runtime.h>
#include <hip/hip_bf16.h>

// Causal conv1d as bf16-MFMA batched GEMM, 8-phase counted-vmcnt schedule.
// out[b,h,t] = sum_{c,k} x[b,c,t+k-3] * W[h, c*4+k] + bias[h]
// B=8, C=256, T=4096, H=512, K=4

#define Bb 8
#define Cc 256
#define Tt 4096
#define Hh 512
#define Kk 4

typedef __attribute__((ext_vector_type(8))) short bf16x8;
typedef __attribute__((ext_vector_type(4))) float f32x4;

// ---------------- workspace layout ----------------
#define WS_XT_OFF   0
#define WS_WT_OFF   16777216
#define WS_ZERO_OFF 17825792
#define WS_NEEDED   17826816ULL   // + 1KB zero page

__device__ __forceinline__ void gload16(const void* g, void* l) {
    __builtin_amdgcn_global_load_lds(
        (const __attribute__((address_space(1))) void*)g,
        (__attribute__((address_space(3))) void*)l, 16, 0, 0);
}

// ---------- prep 1: W[h, c*4+k] f32 -> Wt[k][h][c] bf16, + 1KB zero page ----------
__global__ __launch_bounds__(256) void wt_prep_kernel(const float* __restrict__ W,
                                                      __hip_bfloat16* __restrict__ Wt,
                                                      float* __restrict__ zeros) {
    int n = blockIdx.x * 256 + threadIdx.x;           // [0, 4*512*256)
    int c = n & 255;
    int h = (n >> 8) & 511;
    int k = n >> 17;
    Wt[n] = __float2bfloat16(W[h * (Cc * Kk) + c * Kk + k]);
    if (blockIdx.x == 0) zeros[threadIdx.x] = 0.f;    // 256 floats = 1 KB
}

// ---------- prep 2: x[b][c][t] f32 -> xT[b][t][c] bf16 (LDS tile transpose) ----------
__global__ __launch_bounds__(256) void xt_prep_kernel(const float* __restrict__ x,
                                                      __hip_bfloat16* __restrict__ xT) {
    __shared__ __hip_bfloat16 tile[64][66];           // +2 pad
    const int t0 = blockIdx.x * 64, c0 = blockIdx.y * 64, b = blockIdx.z;
    const int lt = threadIdx.x & 63, lw = threadIdx.x >> 6;
#pragma unroll
    for (int i = 0; i < 16; ++i) {
        int cc = lw + i * 4;
        tile[cc][lt] = __float2bfloat16(x[((size_t)(b * Cc + c0 + cc)) * Tt + t0 + lt]);
    }
    __syncthreads();
#pragma unroll
    for (int i = 0; i < 16; ++i) {
        int tt = lw + i * 4;
        xT[((size_t)(b * Tt + t0 + tt)) * Cc + c0 + lt] = tile[lt][tt];
    }
}

// ---------- main: BM=128(h) x BN=256(t), BK=32 ch x 4 conv-k, 8 waves ----------
// LDS per buffer: A [4k][4cg][128h][16B] = 32768 B ; B [4cg][264t][16B] = 16896 B
// cg strides (2048 / 4224 B) are 0 mod 128B -> fragment ds_read_b128 conflict-free.
#define BUF_BYTES 49664
#define B_OFF     32768
#define LDS_TOTAL (3 * BUF_BYTES)   // 148992 <= 160 KiB

#define STG_A(s2, i) gload16(asrc[i] + (s2) * 64, smem + ((s2) % 3) * BUF_BYTES + adst[i])
#define STG_B(s2, i) gload16(bsrc[i] + (s2) * 64, smem + ((s2) % 3) * BUF_BYTES + bdst[i])

// phase: ds_read frags -> issue stage -> barrier -> lgkm(0) -> setprio MFMA
#define PHASE(s, k, DOSTAGE) do {                                                          \
    const char* bufp = smem + ((s) % 3) * BUF_BYTES;                                       \
    bf16x8 af[4], bfr[4];                                                                  \
    _Pragma("unroll") for (int i = 0; i < 4; ++i)                                          \
        af[i] = *(const bf16x8*)(bufp + (k) * 8192 + aoff_rd + i * 256);                   \
    _Pragma("unroll") for (int j = 0; j < 4; ++j)                                          \
        bfr[j] = *(const bf16x8*)(bufp + boff_rd + ((j) * 16 + (k)) * 16);                 \
    DOSTAGE;                                                                               \
    __builtin_amdgcn_s_barrier();                                                          \
    asm volatile("s_waitcnt lgkmcnt(0)" ::: "memory");                                     \
    __builtin_amdgcn_sched_barrier(0);                                                     \
    __builtin_amdgcn_s_setprio(1);                                                         \
    _Pragma("unroll") for (int i = 0; i < 4; ++i)                                          \
        _Pragma("unroll") for (int j = 0; j < 4; ++j)                                      \
            acc[i][j] = __builtin_amdgcn_mfma_f32_16x16x32_bf16(af[i], bfr[j],             \
                                                                acc[i][j], 0, 0, 0);       \
    __builtin_amdgcn_s_setprio(0);                                                         \
} while (0)

__global__ __launch_bounds__(512, 2) void conv_mfma_kernel(
    const __hip_bfloat16* __restrict__ xT,
    const __hip_bfloat16* __restrict__ Wt,
    const float* __restrict__ bias,
    const float* __restrict__ zeros,
    float* __restrict__ out)
{
    __shared__ __align__(1024) char smem[LDS_TOTAL];
    const int tid  = threadIdx.x;
    const int lane = tid & 63;
    const int wave = tid >> 6;
    const int wr = wave >> 2, wc = wave & 3;          // 2(M) x 4(N) wave grid
    const int l15 = lane & 15, lg = lane >> 4;
    const int t0 = blockIdx.x * 256;
    const int h0 = blockIdx.y * 128;
    const int b  = blockIdx.z;

    // ---- per-thread staging descriptors (fixed; sources advance +64B/step) ----
    const char* asrc[4];
    int adst[4];
#pragma unroll
    for (int i = 0; i < 4; ++i) {
        int sA = tid + i * 512;                        // 0..2047
        int k = sA >> 9, cg = (sA >> 7) & 3, h = sA & 127;
        asrc[i] = (const char*)Wt + (((size_t)(k * Hh + h0 + h)) * Cc + cg * 8) * 2;
        adst[i] = sA * 16;
    }
    const char* bsrc[3];
    int bdst[3];
#pragma unroll
    for (int i = 0; i < 3; ++i) {
        int sB = tid + i * 512;                        // 0..1535; valid slots 0..1055
        if (i == 2 && tid >= 32) sB = tid;             // duplicate inst-0 slot (uniform vmcnt)
        int cg = sB / 264, r = sB - cg * 264;          // B rows r=0..258 <-> t = t0-3+r
        int tg = t0 - 3 + r;
        bool oob = (r > 258) || (tg < 0);
        bsrc[i] = oob ? (const char*)zeros
                      : (const char*)xT + (((size_t)(b * Tt + tg)) * Cc + cg * 8) * 2;
        bdst[i] = B_OFF + sB * 16;
    }

    f32x4 acc[4][4] = {};
    const int aoff_rd = lg * 2048 + (wr * 64 + l15) * 16;         // + k*8192 + i*256
    const int boff_rd = B_OFF + lg * 4224 + (wc * 64 + l15) * 16; // + (j*16+k)*16

    // ---- prologue: stage buffers 0 and 1 ----
#pragma unroll
    for (int i = 0; i < 4; ++i) STG_A(0, i);
#pragma unroll
    for (int i = 0; i < 3; ++i) STG_B(0, i);
#pragma unroll
    for (int i = 0; i < 4; ++i) STG_A(1, i);
#pragma unroll
    for (int i = 0; i < 3; ++i) STG_B(1, i);
    asm volatile("s_waitcnt vmcnt(7)" ::: "memory");   // buf0 landed, buf1 in flight
    __builtin_amdgcn_s_barrier();

    // ---- main loop: 8 K-steps x 4 conv-k phases ----
#pragma unroll
    for (int s = 0; s < 8; ++s) {
        PHASE(s, 0, if (s < 6) { STG_A(s + 2, 0); STG_A(s + 2, 1); });
        __builtin_amdgcn_s_barrier();
        PHASE(s, 1, if (s < 6) { STG_A(s + 2, 2); STG_A(s + 2, 3); });
        __builtin_amdgcn_s_barrier();
        PHASE(s, 2, if (s < 6) { STG_B(s + 2, 0); STG_B(s + 2, 1); });
        __builtin_amdgcn_s_barrier();
        PHASE(s, 3, if (s < 6) { STG_B(s + 2, 2); });
        if (s < 6)       asm volatile("s_waitcnt vmcnt(7)" ::: "memory");
        else if (s == 6) asm volatile("s_waitcnt vmcnt(0)" ::: "memory");
        if (s < 7) __builtin_amdgcn_s_barrier();
    }

    // ---- epilogue: D row=(lg*4+q) -> h, col=l15 -> t ----
#pragma unroll
    for (int i = 0; i < 4; ++i) {
        int hb = h0 + wr * 64 + i * 16 + lg * 4;
        float4 bs = *(const float4*)&bias[hb];
        const float* bsp = (const float*)&bs;
#pragma unroll
        for (int q = 0; q < 4; ++q) {
#pragma unroll
            for (int j = 0; j < 4; ++j) {
                int t = t0 + wc * 64 + j * 16 + l15;
                out[((size_t)(b * Hh + hb + q)) * Tt + t] = acc[i][j][q] + bsp[q];
            }
        }
    }
}

// ---------------- fallback (ws too small): fp32 kernel ----------------
#define TT 256
#define HT 8
#define CT 4
__global__ __launch_bounds__(256) void conv1d_f32_kernel(
    const float* __restrict__ x, const float* __restrict__ W,
    const float* __restrict__ bias, float* __restrict__ out)
{
    const int tid = threadIdx.x;
    const int t0 = blockIdx.x * TT;
    const int h0 = blockIdx.y * HT;
    const int b  = blockIdx.z;
    __shared__ float xs[CT][TT + Kk];
    float acc[HT];
#pragma unroll
    for (int h = 0; h < HT; ++h) acc[h] = 0.f;
    const float* xb = x + (size_t)b * Cc * Tt;
    for (int c0 = 0; c0 < Cc; c0 += CT) {
        __syncthreads();
#pragma unroll
        for (int cc = 0; cc < CT; ++cc)
            for (int j = tid; j < TT + Kk - 1; j += 256) {
                int idx = t0 - (Kk - 1) + j;
                xs[cc][j] = (idx >= 0) ? xb[(size_t)(c0 + cc) * Tt + idx] : 0.f;
            }
        __syncthreads();
#pragma unroll
        for (int cc = 0; cc < CT; ++cc) {
            float xv[Kk];
#pragma unroll
            for (int k = 0; k < Kk; ++k) xv[k] = xs[cc][tid + k];
#pragma unroll
            for (int h = 0; h < HT; ++h) {
                const float* wp = W + (size_t)(h0 + h) * (Cc * Kk) + (size_t)(c0 + cc) * Kk;
#pragma unroll
                for (int k = 0; k < Kk; ++k) acc[h] += wp[k] * xv[k];
            }
        }
    }
#pragma unroll
    for (int h = 0; h < HT; ++h)
        out[((size_t)b * Hh + (h0 + h)) * Tt + t0 + tid] = acc[h] + bias[h0 + h];
}

extern "C" void kernel_launch(void* const* d_in, const int* in_sizes, int n_in,
                              void* d_out, int out_size, void* d_ws, size_t ws_size,
                              hipStream_t stream) {
    const float* x    = (const float*)d_in[0];
    const float* W    = (const float*)d_in[1];
    const float* bias = (const float*)d_in[2];
    float* out        = (float*)d_out;

    if (ws_size >= WS_NEEDED) {
        __hip_bfloat16* xT = (__hip_bfloat16*)((char*)d_ws + WS_XT_OFF);
        __hip_bfloat16* Wt = (__hip_bfloat16*)((char*)d_ws + WS_WT_OFF);
        float* zeros       = (float*)((char*)d_ws + WS_ZERO_OFF);

        wt_prep_kernel<<<dim3((Kk * Hh * Cc) / 256), dim3(256), 0, stream>>>(W, Wt, zeros);
        xt_prep_kernel<<<dim3(Tt / 64, Cc / 64, Bb), dim3(256), 0, stream>>>(x, xT);
        conv_mfma_kernel<<<dim3(Tt / 256, Hh / 128, Bb), dim3(512), 0, stream>>>(xT, Wt, bias, zeros, out);
    } else {
        conv1d_f32_kernel<<<dim3(Tt / TT, Hh / HT, Bb), dim3(256), 0, stream>>>(x, W, bias, out);
    }
}